// Round 1
// baseline (893.220 us; speedup 1.0000x reference)
//
#include <hip/hip_runtime.h>
#include <hip/hip_bf16.h>

#define B_ 2
#define CIN 64
#define HH 96
#define WW 96
#define NC 32
#define HO 94
#define WO 94
#define N_ 8836
#define NPAD 8896
#define NCHUNK 139
#define EPSV 1e-5f
#define SLOPEV 0.01f

typedef __attribute__((ext_vector_type(8))) short short8;
typedef __attribute__((ext_vector_type(4))) float f32x4;

static_assert(NPAD == NCHUNK * 64, "pad");

__device__ __forceinline__ short bf16s(float f) {
  unsigned u = __float_as_uint(f);
  unsigned r = (u + 0x7fffu + ((u >> 16) & 1u)) >> 16;
  return (short)r;
}

// ---------------- conv branches: 3x3 VALID conv + bias + BN + LeakyReLU ----------------
// writes [B][NPAD][32] bf16 (hi), optionally lo residual for split-precision GEMM
__global__ __launch_bounds__(256) void conv_brn(
    const float* __restrict__ x, const float* __restrict__ w,
    const float* __restrict__ bias, const float* __restrict__ g,
    const float* __restrict__ be, const float* __restrict__ m,
    const float* __restrict__ v,
    __hip_bfloat16* __restrict__ ohi, __hip_bfloat16* __restrict__ olo) {
  int n = blockIdx.x * blockDim.x + threadIdx.x;
  int oc = blockIdx.y, b = blockIdx.z;
  if (n >= N_) return;
  int oh = n / WO, ow = n - oh * WO;
  const float* xb = x + ((size_t)b * CIN * HH + oh) * WW + ow;
  const float* wp = w + (size_t)oc * CIN * 9;
  float acc = 0.f;
  for (int ic = 0; ic < CIN; ++ic) {
    const float* xr = xb + (size_t)ic * HH * WW;
#pragma unroll
    for (int kh = 0; kh < 3; ++kh) {
      const float* xq = xr + kh * WW;
      acc += xq[0] * wp[0] + xq[1] * wp[1] + xq[2] * wp[2];
      wp += 3;
    }
  }
  float s = g[oc] * rsqrtf(v[oc] + EPSV);
  float y = (acc + bias[oc] - m[oc]) * s + be[oc];
  y = y > 0.f ? y : SLOPEV * y;
  size_t oidx = ((size_t)b * NPAD + n) * NC + oc;
  __hip_bfloat16 h = __float2bfloat16(y);
  ohi[oidx] = h;
  if (olo) olo[oidx] = __float2bfloat16(y - __bfloat162float(h));
}

// ---------------- softmax stats over n (axis=1): per-m max and 1/denominator ----------------
// block: 4 waves, each owns 16 m's; loops over all n in 64-chunks via MFMA S^T tiles
__global__ __launch_bounds__(256) void attn_stats(
    const __hip_bfloat16* __restrict__ qh, const __hip_bfloat16* __restrict__ ql,
    const __hip_bfloat16* __restrict__ kh_, const __hip_bfloat16* __restrict__ kl,
    float* __restrict__ mxo, float* __restrict__ rdn) {
  int b = blockIdx.y;
  int wave = threadIdx.x >> 6, lane = threadIdx.x & 63;
  int g = lane >> 4, l16 = lane & 15;
  int m16 = blockIdx.x * 64 + wave * 16;
  size_t arow = ((size_t)b * NPAD + m16 + l16) * NC + g * 8;
  short8 akh = *(const short8*)((const short*)kh_ + arow);
  short8 akl = *(const short8*)((const short*)kl + arow);
  const short* qhb = (const short*)qh + (size_t)b * NPAD * NC + g * 8;
  const short* qlb = (const short*)ql + (size_t)b * NPAD * NC + g * 8;
  float mx[4] = {-1e30f, -1e30f, -1e30f, -1e30f};
  float dn[4] = {0.f, 0.f, 0.f, 0.f};
  for (int c = 0; c < NCHUNK; ++c) {
    f32x4 T[4];
#pragma unroll
    for (int nt = 0; nt < 4; ++nt) {
      int n = c * 64 + nt * 16 + l16;
      short8 bh = *(const short8*)(qhb + (size_t)n * NC);
      short8 bl = *(const short8*)(qlb + (size_t)n * NC);
      f32x4 t = __builtin_amdgcn_mfma_f32_16x16x32_bf16(akh, bh, (f32x4){0.f, 0.f, 0.f, 0.f}, 0, 0, 0);
      t = __builtin_amdgcn_mfma_f32_16x16x32_bf16(akh, bl, t, 0, 0, 0);
      t = __builtin_amdgcn_mfma_f32_16x16x32_bf16(akl, bh, t, 0, 0, 0);
      T[nt] = t;
    }
    int nb = c * 64 + l16;
#pragma unroll
    for (int r = 0; r < 4; ++r) {
      float cm = -1e30f;
#pragma unroll
      for (int nt = 0; nt < 4; ++nt)
        cm = fmaxf(cm, (nb + nt * 16 < N_) ? T[nt][r] : -1e30f);
#pragma unroll
      for (int off = 1; off < 16; off <<= 1)
        cm = fmaxf(cm, __shfl_xor(cm, off));
      float nm = fmaxf(mx[r], cm);
      float cs = 0.f;
#pragma unroll
      for (int nt = 0; nt < 4; ++nt)
        if (nb + nt * 16 < N_) cs += __expf(T[nt][r] - nm);
#pragma unroll
      for (int off = 1; off < 16; off <<= 1)
        cs += __shfl_xor(cs, off);
      dn[r] = dn[r] * __expf(mx[r] - nm) + cs;
      mx[r] = nm;
    }
  }
  if (l16 == 0) {
#pragma unroll
    for (int r = 0; r < 4; ++r) {
      size_t mi = (size_t)b * NPAD + m16 + 4 * g + r;
      mxo[mi] = mx[r];
      rdn[mi] = 1.f / dn[r];
    }
  }
}

// ---------------- attention output: o[n,c] = sum_m exp(S[n,m]-mx[m])*rdn[m]*v[m,c] ----------------
__global__ __launch_bounds__(256) void attn_out(
    const __hip_bfloat16* __restrict__ qh, const __hip_bfloat16* __restrict__ ql,
    const __hip_bfloat16* __restrict__ kh_, const __hip_bfloat16* __restrict__ kl,
    const __hip_bfloat16* __restrict__ vbuf,
    const float* __restrict__ mxo, const float* __restrict__ rdn,
    float* __restrict__ ob) {
  int b = blockIdx.y;
  int wave = threadIdx.x >> 6, lane = threadIdx.x & 63;
  int g = lane >> 4, l16 = lane & 15;
  int n16 = blockIdx.x * 64 + wave * 16;
  size_t qrow = ((size_t)b * NPAD + n16 + l16) * NC + g * 8;
  short8 bqh = *(const short8*)((const short*)qh + qrow);
  short8 bql = *(const short8*)((const short*)ql + qrow);
  const short* khb = (const short*)kh_ + (size_t)b * NPAD * NC + g * 8;
  const short* klb = (const short*)kl + (size_t)b * NPAD * NC + g * 8;
  const short* vb = (const short*)vbuf + (size_t)b * NPAD * NC;
  const float* mxb = mxo + (size_t)b * NPAD;
  const float* rdb = rdn + (size_t)b * NPAD;
  f32x4 acc0 = {0.f, 0.f, 0.f, 0.f}, acc1 = {0.f, 0.f, 0.f, 0.f};
  for (int c = 0; c < NCHUNK; ++c) {
    int m64 = c * 64;
    short8 p0, p1;
#pragma unroll
    for (int mt = 0; mt < 4; ++mt) {
      size_t krow = (size_t)(m64 + mt * 16 + l16) * NC;
      short8 ah = *(const short8*)(khb + krow);
      short8 al = *(const short8*)(klb + krow);
      f32x4 t = __builtin_amdgcn_mfma_f32_16x16x32_bf16(ah, bqh, (f32x4){0.f, 0.f, 0.f, 0.f}, 0, 0, 0);
      t = __builtin_amdgcn_mfma_f32_16x16x32_bf16(ah, bql, t, 0, 0, 0);
      t = __builtin_amdgcn_mfma_f32_16x16x32_bf16(al, bqh, t, 0, 0, 0);
#pragma unroll
      for (int r = 0; r < 4; ++r) {
        int m = m64 + mt * 16 + 4 * g + r;
        float p = __expf(t[r] - mxb[m]) * rdb[m];
        short pb = bf16s(p);
        if (mt < 2) p0[mt * 4 + r] = pb;
        else p1[(mt - 2) * 4 + r] = pb;
      }
    }
#pragma unroll
    for (int h = 0; h < 2; ++h) {
      short8 v0, v1;
#pragma unroll
      for (int i = 0; i < 8; ++i) {
        int mr = m64 + h * 32 + 4 * g + (i & 3) + 16 * (i >> 2);
        const short* vp = vb + (size_t)mr * NC + l16;
        v0[i] = vp[0];
        v1[i] = vp[16];
      }
      acc0 = __builtin_amdgcn_mfma_f32_16x16x32_bf16(h ? p1 : p0, v0, acc0, 0, 0, 0);
      acc1 = __builtin_amdgcn_mfma_f32_16x16x32_bf16(h ? p1 : p0, v1, acc1, 0, 0, 0);
    }
  }
#pragma unroll
  for (int r = 0; r < 4; ++r) {
    int n = n16 + 4 * g + r;
    if (n < N_) {
      size_t orow = ((size_t)b * NPAD + n) * NC + l16;
      ob[orow] = acc0[r];
      ob[orow + 16] = acc1[r];
    }
  }
}

// ---------------- fold convT weights: wtf[oc][k9][ic] = wt[ic][oc][k9]*s4[oc]; btf ----------------
__global__ __launch_bounds__(256) void fold_wt(
    const float* __restrict__ wt, const float* __restrict__ bt,
    const float* __restrict__ g4, const float* __restrict__ be4,
    const float* __restrict__ m4, const float* __restrict__ v4,
    float* __restrict__ wtf, float* __restrict__ btf) {
  int idx = blockIdx.x * blockDim.x + threadIdx.x;
  if (idx < CIN * 9 * NC) {
    int oc = idx / (9 * NC);
    int r = idx - oc * (9 * NC);
    int k9 = r / NC, ic = r - k9 * NC;
    float s = g4[oc] * rsqrtf(v4[oc] + EPSV);
    wtf[idx] = wt[((size_t)ic * CIN + oc) * 9 + k9] * s;
  }
  if (idx < CIN) {
    float s = g4[idx] * rsqrtf(v4[idx] + EPSV);
    btf[idx] = (bt[idx] - m4[idx]) * s + be4[idx];
  }
}

// ---------------- convT 3x3 (stride1, "full") + folded BN + LeakyReLU + residual ----------------
__global__ __launch_bounds__(256) void convt_k(
    const float* __restrict__ ob, const float* __restrict__ wtf,
    const float* __restrict__ btf, const float* __restrict__ x,
    float* __restrict__ out) {
  int pq = blockIdx.x * blockDim.x + threadIdx.x;
  int oc = blockIdx.y, b = blockIdx.z;
  int p = pq / WW, q = pq - p * WW;
  float acc = 0.f;
  const float* wb = wtf + (size_t)oc * 9 * NC;
#pragma unroll
  for (int kh = 0; kh < 3; ++kh) {
    int i = p - kh;
    if (i < 0 || i >= HO) continue;
#pragma unroll
    for (int kw = 0; kw < 3; ++kw) {
      int j = q - kw;
      if (j < 0 || j >= WO) continue;
      const float* op = ob + ((size_t)b * NPAD + i * WO + j) * NC;
      const float* wp = wb + (kh * 3 + kw) * NC;
#pragma unroll
      for (int ic = 0; ic < NC; ic += 4) {
        float4 ov = *(const float4*)(op + ic);
        float4 wv = *(const float4*)(wp + ic);
        acc += ov.x * wv.x + ov.y * wv.y + ov.z * wv.z + ov.w * wv.w;
      }
    }
  }
  acc += btf[oc];
  acc = acc > 0.f ? acc : SLOPEV * acc;
  size_t oi = (((size_t)b * CIN + oc) * HH + p) * WW + q;
  out[oi] = x[oi] + acc;
}

extern "C" void kernel_launch(void* const* d_in, const int* in_sizes, int n_in,
                              void* d_out, int out_size, void* d_ws, size_t ws_size,
                              hipStream_t stream) {
  (void)in_sizes; (void)n_in; (void)out_size; (void)ws_size;
  const float* x = (const float*)d_in[0];
  const float* w1 = (const float*)d_in[1];
  const float* b1 = (const float*)d_in[2];
  const float* g1 = (const float*)d_in[3];
  const float* be1 = (const float*)d_in[4];
  const float* m1 = (const float*)d_in[5];
  const float* v1 = (const float*)d_in[6];
  const float* w2 = (const float*)d_in[7];
  const float* b2 = (const float*)d_in[8];
  const float* g2 = (const float*)d_in[9];
  const float* be2 = (const float*)d_in[10];
  const float* m2 = (const float*)d_in[11];
  const float* v2 = (const float*)d_in[12];
  const float* w3 = (const float*)d_in[13];
  const float* b3 = (const float*)d_in[14];
  const float* g3 = (const float*)d_in[15];
  const float* be3 = (const float*)d_in[16];
  const float* m3 = (const float*)d_in[17];
  const float* v3 = (const float*)d_in[18];
  const float* wt = (const float*)d_in[19];
  const float* bt = (const float*)d_in[20];
  const float* g4 = (const float*)d_in[21];
  const float* be4 = (const float*)d_in[22];
  const float* m4 = (const float*)d_in[23];
  const float* v4 = (const float*)d_in[24];

  char* ws = (char*)d_ws;
  constexpr size_t QKVB = (size_t)B_ * NPAD * NC * 2;  // one bf16 buffer, bytes
  __hip_bfloat16* qh = (__hip_bfloat16*)(ws);
  __hip_bfloat16* kh = (__hip_bfloat16*)(ws + QKVB);
  __hip_bfloat16* vb = (__hip_bfloat16*)(ws + 2 * QKVB);
  __hip_bfloat16* ql = (__hip_bfloat16*)(ws + 3 * QKVB);
  __hip_bfloat16* kl = (__hip_bfloat16*)(ws + 4 * QKVB);
  float* mxo = (float*)(ws + 5 * QKVB);
  float* rdn = mxo + (size_t)B_ * NPAD;
  float* ob = rdn + (size_t)B_ * NPAD;
  float* wtf = ob + (size_t)B_ * NPAD * NC;
  float* btf = wtf + CIN * 9 * NC;

  // zero bf16 q/k/v buffers so the NPAD tail rows are zero (masks pad-m via v==0)
  hipMemsetAsync(ws, 0, 5 * QKVB, stream);

  dim3 cgrid((N_ + 255) / 256, NC, B_);
  conv_brn<<<cgrid, 256, 0, stream>>>(x, w1, b1, g1, be1, m1, v1, qh, ql);
  conv_brn<<<cgrid, 256, 0, stream>>>(x, w2, b2, g2, be2, m2, v2, kh, kl);
  conv_brn<<<cgrid, 256, 0, stream>>>(x, w3, b3, g3, be3, m3, v3, vb, nullptr);
  fold_wt<<<(CIN * 9 * NC + 255) / 256, 256, 0, stream>>>(wt, bt, g4, be4, m4, v4, wtf, btf);
  attn_stats<<<dim3(NCHUNK, B_), 256, 0, stream>>>(qh, ql, kh, kl, mxo, rdn);
  attn_out<<<dim3(NCHUNK, B_), 256, 0, stream>>>(qh, ql, kh, kl, vb, mxo, rdn, ob);
  convt_k<<<dim3(HH * WW / 256, CIN, B_), 256, 0, stream>>>(ob, wtf, btf, x, (float*)d_out);
}

// Round 2
// 540.965 us; speedup vs baseline: 1.6512x; 1.6512x over previous
//
#include <hip/hip_runtime.h>
#include <hip/hip_bf16.h>

#define B_ 2
#define CIN 64
#define HH 96
#define WW 96
#define NC 32
#define HO 94
#define WO 94
#define N_ 8836
#define NPAD 8896
#define NCHUNK 139
#define SPLITN 8
#define EPSV 1e-5f
#define SLOPEV 0.01f

typedef __attribute__((ext_vector_type(8))) short short8;
typedef __attribute__((ext_vector_type(4))) float f32x4;

static_assert(NPAD == NCHUNK * 64, "pad");

__device__ __forceinline__ short bf16s(float f) {
  unsigned u = __float_as_uint(f);
  unsigned r = (u + 0x7fffu + ((u >> 16) & 1u)) >> 16;
  return (short)r;
}

// ---------------- conv branches: 3x3 VALID conv + bias + BN + LeakyReLU ----------------
__global__ __launch_bounds__(256) void conv_brn(
    const float* __restrict__ x, const float* __restrict__ w,
    const float* __restrict__ bias, const float* __restrict__ g,
    const float* __restrict__ be, const float* __restrict__ m,
    const float* __restrict__ v,
    __hip_bfloat16* __restrict__ ohi, __hip_bfloat16* __restrict__ olo) {
  int n = blockIdx.x * blockDim.x + threadIdx.x;
  int oc = blockIdx.y, b = blockIdx.z;
  if (n >= N_) return;
  int oh = n / WO, ow = n - oh * WO;
  const float* xb = x + ((size_t)b * CIN * HH + oh) * WW + ow;
  const float* wp = w + (size_t)oc * CIN * 9;
  float acc = 0.f;
  for (int ic = 0; ic < CIN; ++ic) {
    const float* xr = xb + (size_t)ic * HH * WW;
#pragma unroll
    for (int kh = 0; kh < 3; ++kh) {
      const float* xq = xr + kh * WW;
      acc += xq[0] * wp[0] + xq[1] * wp[1] + xq[2] * wp[2];
      wp += 3;
    }
  }
  float s = g[oc] * rsqrtf(v[oc] + EPSV);
  float y = (acc + bias[oc] - m[oc]) * s + be[oc];
  y = y > 0.f ? y : SLOPEV * y;
  size_t oidx = ((size_t)b * NPAD + n) * NC + oc;
  __hip_bfloat16 h = __float2bfloat16(y);
  ohi[oidx] = h;
  if (olo) olo[oidx] = __float2bfloat16(y - __bfloat162float(h));
}

// ---------------- stats pass: per-lane online (mx, dn) over an n-slice ----------------
// grid (m-chunk 139, n-slice 8, B); 4 waves each own a 16-m tile
__global__ __launch_bounds__(256) void attn_stats(
    const __hip_bfloat16* __restrict__ qh, const __hip_bfloat16* __restrict__ ql,
    const __hip_bfloat16* __restrict__ kh_, const __hip_bfloat16* __restrict__ kl,
    float* __restrict__ pmx, float* __restrict__ pdn) {
  int s = blockIdx.y, b = blockIdx.z;
  int wave = threadIdx.x >> 6, lane = threadIdx.x & 63;
  int g = lane >> 4, l16 = lane & 15;
  int m16 = blockIdx.x * 64 + wave * 16;
  size_t arow = ((size_t)b * NPAD + m16 + l16) * NC + g * 8;
  short8 akh = *(const short8*)((const short*)kh_ + arow);
  short8 akl = *(const short8*)((const short*)kl + arow);
  const short* qhb = (const short*)qh + (size_t)b * NPAD * NC + g * 8;
  const short* qlb = (const short*)ql + (size_t)b * NPAD * NC + g * 8;
  float mx[4] = {-1e30f, -1e30f, -1e30f, -1e30f};
  float dn[4] = {0.f, 0.f, 0.f, 0.f};
  for (int c = s; c < NCHUNK; c += SPLITN) {
    f32x4 T[4];
#pragma unroll
    for (int nt = 0; nt < 4; ++nt) {
      int n = c * 64 + nt * 16 + l16;
      short8 bh = *(const short8*)(qhb + (size_t)n * NC);
      short8 bl = *(const short8*)(qlb + (size_t)n * NC);
      f32x4 t = __builtin_amdgcn_mfma_f32_16x16x32_bf16(akh, bh, (f32x4){0.f, 0.f, 0.f, 0.f}, 0, 0, 0);
      t = __builtin_amdgcn_mfma_f32_16x16x32_bf16(akh, bl, t, 0, 0, 0);
      t = __builtin_amdgcn_mfma_f32_16x16x32_bf16(akl, bh, t, 0, 0, 0);
      T[nt] = t;
    }
    if (c == NCHUNK - 1) {
#pragma unroll
      for (int nt = 0; nt < 4; ++nt)
        if (c * 64 + nt * 16 + l16 >= N_)
          T[nt] = (f32x4){-1e30f, -1e30f, -1e30f, -1e30f};
    }
#pragma unroll
    for (int r = 0; r < 4; ++r) {
      float cm = fmaxf(fmaxf(T[0][r], T[1][r]), fmaxf(T[2][r], T[3][r]));
      float nm = fmaxf(mx[r], cm);
      float cs = __expf(T[0][r] - nm) + __expf(T[1][r] - nm) +
                 __expf(T[2][r] - nm) + __expf(T[3][r] - nm);
      dn[r] = dn[r] * __expf(mx[r] - nm) + cs;
      mx[r] = nm;
    }
  }
#pragma unroll
  for (int r = 0; r < 4; ++r) {
#pragma unroll
    for (int off = 1; off < 16; off <<= 1) {
      float omx = __shfl_xor(mx[r], off);
      float odn = __shfl_xor(dn[r], off);
      float nm = fmaxf(mx[r], omx);
      dn[r] = dn[r] * __expf(mx[r] - nm) + odn * __expf(omx - nm);
      mx[r] = nm;
    }
    if (l16 == 0) {
      size_t mi = ((size_t)s * B_ + b) * NPAD + m16 + 4 * g + r;
      pmx[mi] = mx[r];
      pdn[mi] = dn[r];
    }
  }
}

// ---------------- merge the 8 partial (mx, dn) into mx and 1/dn ----------------
__global__ __launch_bounds__(256) void combine_stats(
    const float* __restrict__ pmx, const float* __restrict__ pdn,
    float* __restrict__ mxo, float* __restrict__ rdn) {
  int idx = blockIdx.x * blockDim.x + threadIdx.x;
  if (idx >= B_ * NPAD) return;
  int b = idx / NPAD, m = idx - b * NPAD;
  float pm[SPLITN];
  float mx = -1e30f;
#pragma unroll
  for (int s = 0; s < SPLITN; ++s) {
    pm[s] = pmx[((size_t)s * B_ + b) * NPAD + m];
    mx = fmaxf(mx, pm[s]);
  }
  float dn = 0.f;
#pragma unroll
  for (int s = 0; s < SPLITN; ++s)
    dn += pdn[((size_t)s * B_ + b) * NPAD + m] * __expf(pm[s] - mx);
  mxo[idx] = mx;
  rdn[idx] = 1.f / dn;
}

// ---------------- pack V (with rdn folded) into PV B-fragment layout ----------------
// vp[((b*NCHUNK + c)*2 + h)*2 + cc][lane][j] : m = c*64+h*32+16*(j>>2)+4g+(j&3), col = cc*16+l16
__global__ __launch_bounds__(256) void pack_v(
    const __hip_bfloat16* __restrict__ vb, const float* __restrict__ rdn,
    __hip_bfloat16* __restrict__ vp) {
  int idx = blockIdx.x * blockDim.x + threadIdx.x;
  if (idx >= B_ * NCHUNK * 4 * 64) return;
  int lane = idx & 63;
  int cc = (idx >> 6) & 1;
  int h = (idx >> 7) & 1;
  int t = idx >> 8;
  int c = t % NCHUNK, b = t / NCHUNK;
  int g = lane >> 4, l16 = lane & 15;
  int col = cc * 16 + l16;
  short8 o;
#pragma unroll
  for (int j = 0; j < 8; ++j) {
    int m = c * 64 + h * 32 + 16 * (j >> 2) + 4 * g + (j & 3);
    size_t mi = (size_t)b * NPAD + m;
    float vv = __bfloat162float(vb[mi * NC + col]) * rdn[mi];
    o[j] = bf16s(vv);
  }
  *(short8*)((short*)vp + (size_t)idx * 8) = o;
}

// ---------------- attention output (m-split partials): o_s[n,c] ----------------
__global__ __launch_bounds__(256) void attn_out(
    const __hip_bfloat16* __restrict__ qh, const __hip_bfloat16* __restrict__ ql,
    const __hip_bfloat16* __restrict__ kh_, const __hip_bfloat16* __restrict__ kl,
    const __hip_bfloat16* __restrict__ vp,
    const float* __restrict__ mxo,
    float* __restrict__ op, int splitm) {
  int s = blockIdx.y, b = blockIdx.z;
  int wave = threadIdx.x >> 6, lane = threadIdx.x & 63;
  int g = lane >> 4, l16 = lane & 15;
  int n16 = blockIdx.x * 64 + wave * 16;
  size_t qrow = ((size_t)b * NPAD + n16 + l16) * NC + g * 8;
  short8 bqh = *(const short8*)((const short*)qh + qrow);
  short8 bql = *(const short8*)((const short*)ql + qrow);
  const short* khb = (const short*)kh_ + (size_t)b * NPAD * NC + g * 8;
  const short* klb = (const short*)kl + (size_t)b * NPAD * NC + g * 8;
  const short* vpb = (const short*)vp + (size_t)b * NCHUNK * 4 * 64 * 8;
  const float* mxb = mxo + (size_t)b * NPAD;
  f32x4 acc0 = {0.f, 0.f, 0.f, 0.f}, acc1 = {0.f, 0.f, 0.f, 0.f};
  for (int c = s; c < NCHUNK; c += splitm) {
    int m64 = c * 64;
    short8 p0, p1;
#pragma unroll
    for (int mt = 0; mt < 4; ++mt) {
      size_t krow = (size_t)(m64 + mt * 16 + l16) * NC;
      short8 ah = *(const short8*)(khb + krow);
      short8 al = *(const short8*)(klb + krow);
      f32x4 t = __builtin_amdgcn_mfma_f32_16x16x32_bf16(ah, bqh, (f32x4){0.f, 0.f, 0.f, 0.f}, 0, 0, 0);
      t = __builtin_amdgcn_mfma_f32_16x16x32_bf16(ah, bql, t, 0, 0, 0);
      t = __builtin_amdgcn_mfma_f32_16x16x32_bf16(al, bqh, t, 0, 0, 0);
      f32x4 mxv = *(const f32x4*)(mxb + m64 + mt * 16 + 4 * g);
#pragma unroll
      for (int r = 0; r < 4; ++r) {
        short pb = bf16s(__expf(t[r] - mxv[r]));
        if (mt < 2) p0[mt * 4 + r] = pb;
        else p1[(mt - 2) * 4 + r] = pb;
      }
    }
    const short* vc = vpb + (size_t)c * 4 * 64 * 8 + (size_t)lane * 8;
    short8 v00 = *(const short8*)(vc);
    short8 v01 = *(const short8*)(vc + 512);
    short8 v10 = *(const short8*)(vc + 1024);
    short8 v11 = *(const short8*)(vc + 1536);
    acc0 = __builtin_amdgcn_mfma_f32_16x16x32_bf16(p0, v00, acc0, 0, 0, 0);
    acc1 = __builtin_amdgcn_mfma_f32_16x16x32_bf16(p0, v01, acc1, 0, 0, 0);
    acc0 = __builtin_amdgcn_mfma_f32_16x16x32_bf16(p1, v10, acc0, 0, 0, 0);
    acc1 = __builtin_amdgcn_mfma_f32_16x16x32_bf16(p1, v11, acc1, 0, 0, 0);
  }
#pragma unroll
  for (int r = 0; r < 4; ++r) {
    int n = n16 + 4 * g + r;
    if (n < N_) {
      size_t orow = (((size_t)s * B_ + b) * NPAD + n) * NC + l16;
      op[orow] = acc0[r];
      op[orow + 16] = acc1[r];
    }
  }
}

// ---------------- sum the m-split partials ----------------
__global__ __launch_bounds__(256) void combine_o(
    const float* __restrict__ op, float* __restrict__ ob, int splitm) {
  int idx = blockIdx.x * blockDim.x + threadIdx.x;
  if (idx >= B_ * NPAD * NC / 4) return;
  f32x4 acc = {0.f, 0.f, 0.f, 0.f};
  for (int s = 0; s < splitm; ++s) {
    f32x4 v = *(const f32x4*)(op + (size_t)s * B_ * NPAD * NC + (size_t)idx * 4);
    acc += v;
  }
  *(f32x4*)(ob + (size_t)idx * 4) = acc;
}

// ---------------- fold convT weights ----------------
__global__ __launch_bounds__(256) void fold_wt(
    const float* __restrict__ wt, const float* __restrict__ bt,
    const float* __restrict__ g4, const float* __restrict__ be4,
    const float* __restrict__ m4, const float* __restrict__ v4,
    float* __restrict__ wtf, float* __restrict__ btf) {
  int idx = blockIdx.x * blockDim.x + threadIdx.x;
  if (idx < CIN * 9 * NC) {
    int oc = idx / (9 * NC);
    int r = idx - oc * (9 * NC);
    int k9 = r / NC, ic = r - k9 * NC;
    float s = g4[oc] * rsqrtf(v4[oc] + EPSV);
    wtf[idx] = wt[((size_t)ic * CIN + oc) * 9 + k9] * s;
  }
  if (idx < CIN) {
    float s = g4[idx] * rsqrtf(v4[idx] + EPSV);
    btf[idx] = (bt[idx] - m4[idx]) * s + be4[idx];
  }
}

// ---------------- convT 3x3 + folded BN + LeakyReLU + residual ----------------
__global__ __launch_bounds__(256) void convt_k(
    const float* __restrict__ ob, const float* __restrict__ wtf,
    const float* __restrict__ btf, const float* __restrict__ x,
    float* __restrict__ out) {
  int pq = blockIdx.x * blockDim.x + threadIdx.x;
  int oc = blockIdx.y, b = blockIdx.z;
  int p = pq / WW, q = pq - p * WW;
  float acc = 0.f;
  const float* wb = wtf + (size_t)oc * 9 * NC;
#pragma unroll
  for (int kh = 0; kh < 3; ++kh) {
    int i = p - kh;
    if (i < 0 || i >= HO) continue;
#pragma unroll
    for (int kw = 0; kw < 3; ++kw) {
      int j = q - kw;
      if (j < 0 || j >= WO) continue;
      const float* opx = ob + ((size_t)b * NPAD + i * WO + j) * NC;
      const float* wp = wb + (kh * 3 + kw) * NC;
#pragma unroll
      for (int ic = 0; ic < NC; ic += 4) {
        float4 ov = *(const float4*)(opx + ic);
        float4 wv = *(const float4*)(wp + ic);
        acc += ov.x * wv.x + ov.y * wv.y + ov.z * wv.z + ov.w * wv.w;
      }
    }
  }
  acc += btf[oc];
  acc = acc > 0.f ? acc : SLOPEV * acc;
  size_t oi = (((size_t)b * CIN + oc) * HH + p) * WW + q;
  out[oi] = x[oi] + acc;
}

extern "C" void kernel_launch(void* const* d_in, const int* in_sizes, int n_in,
                              void* d_out, int out_size, void* d_ws, size_t ws_size,
                              hipStream_t stream) {
  (void)in_sizes; (void)n_in; (void)out_size;
  const float* x = (const float*)d_in[0];
  const float* w1 = (const float*)d_in[1];
  const float* b1 = (const float*)d_in[2];
  const float* g1 = (const float*)d_in[3];
  const float* be1 = (const float*)d_in[4];
  const float* m1 = (const float*)d_in[5];
  const float* v1 = (const float*)d_in[6];
  const float* w2 = (const float*)d_in[7];
  const float* b2 = (const float*)d_in[8];
  const float* g2 = (const float*)d_in[9];
  const float* be2 = (const float*)d_in[10];
  const float* m2 = (const float*)d_in[11];
  const float* v2 = (const float*)d_in[12];
  const float* w3 = (const float*)d_in[13];
  const float* b3 = (const float*)d_in[14];
  const float* g3 = (const float*)d_in[15];
  const float* be3 = (const float*)d_in[16];
  const float* m3 = (const float*)d_in[17];
  const float* v3 = (const float*)d_in[18];
  const float* wt = (const float*)d_in[19];
  const float* bt = (const float*)d_in[20];
  const float* g4 = (const float*)d_in[21];
  const float* be4 = (const float*)d_in[22];
  const float* m4 = (const float*)d_in[23];
  const float* v4 = (const float*)d_in[24];

  char* ws = (char*)d_ws;
  constexpr size_t NB = (size_t)B_ * NPAD * NC * 2;  // one bf16 buffer, bytes
  __hip_bfloat16* qh = (__hip_bfloat16*)(ws);
  __hip_bfloat16* kh = (__hip_bfloat16*)(ws + NB);
  __hip_bfloat16* vb = (__hip_bfloat16*)(ws + 2 * NB);
  __hip_bfloat16* ql = (__hip_bfloat16*)(ws + 3 * NB);
  __hip_bfloat16* kl = (__hip_bfloat16*)(ws + 4 * NB);
  __hip_bfloat16* vp = (__hip_bfloat16*)(ws + 5 * NB);
  float* mxo = (float*)(ws + 6 * NB);
  float* rdn = mxo + (size_t)B_ * NPAD;
  float* pmx = rdn + (size_t)B_ * NPAD;
  float* pdn = pmx + (size_t)SPLITN * B_ * NPAD;
  float* ob = pdn + (size_t)SPLITN * B_ * NPAD;
  float* wtf = ob + (size_t)B_ * NPAD * NC;
  float* btf = wtf + CIN * 9 * NC;
  float* opart = btf + CIN;
  size_t base = (size_t)((char*)opart - ws);
  constexpr size_t OBB = (size_t)B_ * NPAD * NC * 4;  // one f32 o-buffer, bytes
  int splitm = 1;
  float* opdst = ob;
  if (ws_size >= base + 4 * OBB) { splitm = 4; opdst = opart; }
  else if (ws_size >= base + 2 * OBB) { splitm = 2; opdst = opart; }

  // zero bf16 q/k/v buffers so the NPAD tail rows are zero
  hipMemsetAsync(ws, 0, 5 * NB, stream);

  dim3 cgrid((N_ + 255) / 256, NC, B_);
  conv_brn<<<cgrid, 256, 0, stream>>>(x, w1, b1, g1, be1, m1, v1, qh, ql);
  conv_brn<<<cgrid, 256, 0, stream>>>(x, w2, b2, g2, be2, m2, v2, kh, kl);
  conv_brn<<<cgrid, 256, 0, stream>>>(x, w3, b3, g3, be3, m3, v3, vb, nullptr);
  fold_wt<<<(CIN * 9 * NC + 255) / 256, 256, 0, stream>>>(wt, bt, g4, be4, m4, v4, wtf, btf);
  attn_stats<<<dim3(NCHUNK, SPLITN, B_), 256, 0, stream>>>(qh, ql, kh, kl, pmx, pdn);
  combine_stats<<<(B_ * NPAD + 255) / 256, 256, 0, stream>>>(pmx, pdn, mxo, rdn);
  pack_v<<<(B_ * NCHUNK * 4 * 64 + 255) / 256, 256, 0, stream>>>(vb, rdn, vp);
  attn_out<<<dim3(NCHUNK, splitm, B_), 256, 0, stream>>>(qh, ql, kh, kl, vp, mxo, opdst, splitm);
  if (splitm > 1)
    combine_o<<<(B_ * NPAD * NC / 4 + 255) / 256, 256, 0, stream>>>(opdst, ob, splitm);
  convt_k<<<dim3(HH * WW / 256, CIN, B_), 256, 0, stream>>>(ob, wtf, btf, x, (float*)d_out);
}